// Round 4
// baseline (657.110 us; speedup 1.0000x reference)
//
#include <hip/hip_runtime.h>
#include <math.h>

#define CC 512
#define BB 8
#define TTOT 8192
#define LEN1 (TTOT - 2)   // 8190
#define LEN2 (TTOT - 4)   // 8188
#define GPRE 8
#define GPOST 24
#define PITCH (GPRE + TTOT + GPOST)   // 8224 storage rows
#define CHST (PITCH * 32)             // u16 per (batch,chunk) plane
#define BST (PITCH * 512)             // u16 per batch (16 chunks)

typedef unsigned short u16;
typedef __bf16 v8bf __attribute__((ext_vector_type(8)));
typedef float v4f __attribute__((ext_vector_type(4)));

__device__ __forceinline__ u16 f2b(float f) {
    unsigned u = __float_as_uint(f);
    unsigned r = (u + 0x7FFFu + ((u >> 16) & 1u)) >> 16;
    return (u16)r;
}
__device__ __forceinline__ float b2f(u16 h) {
    return __uint_as_float(((unsigned)h) << 16);
}
__device__ __forceinline__ void ldsdma16(const void* g, void* l) {
    __builtin_amdgcn_global_load_lds(
        (const __attribute__((address_space(1))) unsigned int*)g,
        (__attribute__((address_space(3))) unsigned int*)l, 16, 0, 0);
}

// ---------------------------------------------------------------------------
// X layout (xTa/xTb): [b][ci>>5][R][32ci] with R = GPRE + t (storage row).
// Within a row's 64B, granule g=(ci>>3)&3 is stored at slot s = g ^ ((R>>1)&3)
// (bank-conflict-free ds_read_b128 in convg; involution, read uses same XOR).
// W layout (wr): [ci>>5][k][co][32ci], slot s = g ^ ((co>>1)&3).
// ---------------------------------------------------------------------------

// Weight prep: w[co][ci][3] f32 -> chunked/swizzled bf16
__global__ __launch_bounds__(256) void wprep_kernel(const float* __restrict__ w,
                                                    u16* __restrict__ wr)
{
    int idx = blockIdx.x * 256 + threadIdx.x;     // co*512 + ci
    int co = idx >> 9, ci = idx & 511;
    const float* s = w + (size_t)idx * 3;
    int g = (ci >> 3) & 3;
    int slot = ((g ^ ((co >> 1) & 3)) << 3) | (ci & 7);
    size_t base = (size_t)(ci >> 5) * 3 * 16384 + (size_t)co * 32 + slot;
#pragma unroll
    for (int k = 0; k < 3; ++k)
        wr[base + (size_t)k * 16384] = f2b(s[k]);
}

// Zero guard rows R in [0,GPRE) and [GPRE+Lstart, GPRE+Lstart+GPOST), all chunks.
__global__ __launch_bounds__(256) void zguard_kernel(u16* x0, int Lstart)
{
    int r = blockIdx.x;            // 0..31
    int b = blockIdx.y;
    int R = (r < GPRE) ? r : (GPRE + Lstart + (r - GPRE));
    unsigned* p = (unsigned*)(x0 + (size_t)b * BST);
    int chunk = threadIdx.x >> 4, off = threadIdx.x & 15;
    p[(size_t)chunk * (CHST / 2) + (size_t)R * 16 + off] = 0u;
}

// ---------------------------------------------------------------------------
// Fused activation1d: coalesced LDS staging + register-ring streaming compute.
// (unchanged from round 3 — harness-verified)
// ---------------------------------------------------------------------------
template<bool TMAJ>
__global__ __launch_bounds__(256) void actS_kernel(
    const void* __restrict__ xin_v,
    u16* __restrict__ yout,          // storage base (R=0) of batch 0
    const float* __restrict__ up_w,  // [2C][6]
    const float* __restrict__ down_w,// [C][12]
    const float* __restrict__ alpha,
    const float* __restrict__ beta,
    int Lin)
{
    const int Lout = Lin - 2;
    const int smax = 2 * Lin - 4;
    const int tid  = threadIdx.x;
    const int cs   = tid & 31;           // channel within chunk
    const int tseg = tid >> 5;           // 0..7, 16 outputs each
    const int chunk = blockIdx.y;
    const int b     = blockIdx.z;
    const int T0    = blockIdx.x * 128;
    const int Tt    = T0 + tseg * 16;
    const int cg    = chunk * 32 + cs;

    __shared__ float xs[32 * 141];       // [c][i], 139 used per row

    // ---- stage x window g in [T0-4, T0+135) ----
    if (!TMAJ) {
        const float* xcb = (const float*)xin_v + ((size_t)b * CC + chunk * 32) * (size_t)Lin;
        int lane = tid & 63, w = tid >> 6;
#pragma unroll
        for (int rr = 0; rr < 8; ++rr) {
            int c = w * 8 + rr;
            const float* xr = xcb + (size_t)c * Lin;
            for (int i = lane; i < 139; i += 64) {
                int g = T0 - 4 + i;
                xs[c * 141 + i] = (g >= 0 && g < Lin) ? xr[g] : 0.0f;
            }
        }
    } else {
        const u16* xb = (const u16*)xin_v + (size_t)b * BST + (size_t)chunk * CHST;
        int pr = tid & 15, rq = tid >> 4;
#pragma unroll
        for (int r0 = 0; r0 < 139; r0 += 16) {
            int row = r0 + rq;
            if (row < 139) {
                int R = GPRE + T0 - 4 + row;   // guards cover both ends
                unsigned u = *((const unsigned*)(xb + (size_t)R * 32) + pr);
                int p2 = pr * 2;
                int c = (((p2 >> 3) ^ ((R >> 1) & 3)) << 3) | (p2 & 7);  // de-swizzle
                xs[c * 141 + row]       = b2f((u16)(u & 0xFFFFu));
                xs[(c + 1) * 141 + row] = b2f((u16)(u >> 16));
            }
        }
    }
    __syncthreads();

    // ---- per-thread register-ring compute ----
    const float a     = expf(alpha[cg]);
    const float inv2b = 1.0f / (2.0f * expf(beta[cg]) + 1e-9f);
    float uwa[6], uwb[6], dw[12];
#pragma unroll
    for (int k = 0; k < 6; ++k) {
        uwa[k] = up_w[(2 * cg) * 6 + k];
        uwb[k] = up_w[(2 * cg + 1) * 6 + k];
    }
#pragma unroll
    for (int j = 0; j < 12; ++j) dw[j] = down_w[cg * 12 + j];

    const float* xrow = xs + cs * 141 + tseg * 16;   // xrow[j] = x[Tt-4+j]

    float xw[12], sr[12];

    auto sval = [&](int idx) -> float {              // idx compile-time after unroll
        int s  = 2 * Tt - 5 + idx;
        int xo = (idx + 1) >> 1;
        float u = 0.0f;
#pragma unroll
        for (int k = 0; k < 6; ++k) {
            float wk = (idx & 1) ? uwa[k] : uwb[k];
            u = fmaf(xw[(xo + k) % 12], wk, u);
        }
        float v = fmaf(1.0f - __cosf(2.0f * a * u), inv2b, u);
        return (s >= 0 && s < smax) ? v : 0.0f;
    };

    // prologue: xw holds x[Tt-4 .. Tt+6]
#pragma unroll
    for (int j = 0; j < 11; ++j) xw[j] = xrow[j];
    xw[11] = 0.0f;
#pragma unroll
    for (int idx = 0; idx < 10; ++idx) sr[idx] = sval(idx);

    u16* yb = yout + (size_t)b * BST + (size_t)chunk * CHST;

#pragma unroll
    for (int i = 0; i < 16; ++i) {
        xw[(11 + i) % 12] = xrow[11 + i];            // x[Tt+7+i]
        sr[(10 + 2 * i) % 12] = sval(10 + 2 * i);
        sr[(11 + 2 * i) % 12] = sval(11 + 2 * i);
        float y = 0.0f;
#pragma unroll
        for (int j = 0; j < 12; ++j)
            y = fmaf(sr[(2 * i + j) % 12], dw[j], y);
        int t = Tt + i;
        if (t < Lout) {
            int R = GPRE + t;
            int slot = (((cs >> 3) ^ ((R >> 1) & 3)) << 3) | (cs & 7);
            yb[(size_t)R * 32 + slot] = f2b(y);
        }
    }
}

// ---------------------------------------------------------------------------
// k=3 pad=1 conv as bf16 MFMA GEMM, double-buffered LDS + counted vmcnt.
// 512 threads (8 waves), tile 256t x 256co, K-step 32 ci (16 steps).
// Each wave: 128t x 64co (wt = wid&1, wc = wid>>2..). Per cig each wave issues
// exactly 9 global_load_lds (uniform -> s_waitcnt vmcnt(9) is legal): prefetch
// for cig+1 stays in flight across the raw s_barrier while cig's MFMAs run.
// ---------------------------------------------------------------------------
template<int ORIENT>
__global__ __launch_bounds__(512, 2) void convg_kernel(
    const u16* __restrict__ xt,     // storage base (R=0) of batch 0
    const u16* __restrict__ wr,     // [16][3][512][32] swizzled bf16
    const float* __restrict__ bias, // [512]
    u16* __restrict__ yt,           // ORIENT 0 output (storage base)
    float* __restrict__ out,        // ORIENT 1 output (B,C,Lout)
    const float* __restrict__ resid,// ORIENT 1 residual (B,C,TTOT)
    int Lout)
{
    const int tid  = threadIdx.x;
    const int lane = tid & 63, wid = tid >> 6;
    const int wt = wid & 1, wc = wid >> 1;      // 2 t-halves x 4 co-quarters
    const int l15 = lane & 15, q = lane >> 4;
    const int t0  = blockIdx.x * 256;
    const int co0 = blockIdx.y * 256;
    const int b   = blockIdx.z;

    __shared__ __align__(16) u16 xsm[2][264 * 32];      // 2 x 16896 B
    __shared__ __align__(16) u16 wsm[2][3 * 256 * 32];  // 2 x 49152 B
    __shared__ __align__(16) u16 dpad[512];             // dummy-DMA scratch (1 KB)

    const u16* xb = xt + (size_t)b * BST;
    const int R0 = GPRE + t0 - 1;   // storage row of LDS row 0 (>= 7)

    v4f acc[8][4];
#pragma unroll
    for (int m = 0; m < 8; ++m)
#pragma unroll
        for (int n = 0; n < 4; ++n)
#pragma unroll
            for (int r = 0; r < 4; ++r) acc[m][n][r] = 0.0f;

    // stage: issue EXACTLY 9 global_load_lds per wave for K-chunk cig into buf sel.
    //   X: 17 ops (1056 granules, rows R0..R0+263, contiguous 16.9 KB)
    //   W: 48 ops (3 k-slabs x 16 ops, contiguous 16 KB each)
    //   waves 1..7 add 1 dummy (wave 0 carries X op 16) -> uniform count 9.
    auto stage = [&](int cig, int sel) {
        const u16* xsl = xb + (size_t)cig * CHST + (size_t)R0 * 32;
        const u16* wsl = wr + (size_t)cig * 49152 + (size_t)co0 * 32;
        u16* xd = &xsm[sel][0];
        u16* wd = &wsm[sel][0];
#pragma unroll
        for (int j = 0; j < 3; ++j) {
            int ii = wid + 8 * j;
            if (ii < 17) {
                if (ii * 64 + lane < 1056)
                    ldsdma16(xsl + (size_t)(ii * 64 + lane) * 8, xd + (size_t)ii * 512);
            }
        }
        if (wid != 0) ldsdma16(xsl + (size_t)lane * 8, &dpad[0]);
#pragma unroll
        for (int j = 0; j < 6; ++j) {
            int ii = wid + 8 * j;    // 0..47: k = ii>>4, slab-op = ii&15
            ldsdma16(wsl + (size_t)(ii >> 4) * 16384
                         + (size_t)((ii & 15) * 64 + lane) * 8,
                     wd + (size_t)ii * 512);
        }
    };

    stage(0, 0);
    int cur = 0;
#pragma unroll 1
    for (int cig = 0; cig < 16; ++cig) {
        if (cig < 15) {
            stage(cig + 1, cur ^ 1);
            __builtin_amdgcn_sched_barrier(0);
            asm volatile("s_waitcnt vmcnt(9)" ::: "memory");   // prev 9 done, new 9 in flight
        } else {
            asm volatile("s_waitcnt vmcnt(0)" ::: "memory");
        }
        __builtin_amdgcn_s_barrier();          // raw: no vmcnt drain
        __builtin_amdgcn_sched_barrier(0);

        const u16* xs = &xsm[cur][0];
        const u16* ws = &wsm[cur][0];
#pragma unroll
        for (int k = 0; k < 3; ++k) {
            v8bf wf[4], xfr[8];
#pragma unroll
            for (int n = 0; n < 4; ++n) {
                int co_l = wc * 64 + n * 16 + l15;
                wf[n] = *(const v8bf*)(ws + ((k * 256 + co_l) << 5)
                                          + ((q ^ ((co_l >> 1) & 3)) << 3));
            }
#pragma unroll
            for (int m = 0; m < 8; ++m) {
                int r = wt * 128 + m * 16 + l15 + k;     // storage row R0+r
                xfr[m] = *(const v8bf*)(xs + (r << 5)
                                           + ((q ^ (((r + 7) >> 1) & 3)) << 3));
            }
            __builtin_amdgcn_s_setprio(1);
#pragma unroll
            for (int m = 0; m < 8; ++m)
#pragma unroll
                for (int n = 0; n < 4; ++n) {
                    if (ORIENT == 0)
                        acc[m][n] = __builtin_amdgcn_mfma_f32_16x16x32_bf16(
                            xfr[m], wf[n], acc[m][n], 0, 0, 0);
                    else
                        acc[m][n] = __builtin_amdgcn_mfma_f32_16x16x32_bf16(
                            wf[n], xfr[m], acc[m][n], 0, 0, 0);
                }
            __builtin_amdgcn_s_setprio(0);
        }
        __builtin_amdgcn_sched_barrier(0);
        __builtin_amdgcn_s_barrier();          // all reads of buf[cur] retired
        cur ^= 1;
    }

    if (ORIENT == 0) {
        // D[m=t][n=co]: col(lane&15)=co, row(q*4+reg)=t-local; write chunk-row bf16
        float bv[4];
#pragma unroll
        for (int n = 0; n < 4; ++n) bv[n] = bias[co0 + wc * 64 + n * 16 + l15];
        u16* yb = yt + (size_t)b * BST;
        int cb = (co0 + wc * 64) >> 5;    // chunk base
#pragma unroll
        for (int m = 0; m < 8; ++m) {
            int tb = t0 + wt * 128 + m * 16;
#pragma unroll
            for (int rg = 0; rg < 4; ++rg) {
                int t = tb + q * 4 + rg;
                if (t < Lout) {
                    int R = GPRE + t;
                    int f = (R >> 1) & 3;
#pragma unroll
                    for (int n = 0; n < 4; ++n) {
                        int cl = ((n & 1) << 4) | l15;
                        int slot = (((cl >> 3) ^ f) << 3) | (cl & 7);
                        yb[(size_t)(cb + (n >> 1)) * CHST + (size_t)R * 32 + slot]
                            = f2b(acc[m][n][rg] + bv[n]);
                    }
                }
            }
        }
    } else {
        // D[m=co][n=t]: col(lane&15)=t-local, row(q*4+reg)=co-local
        float bv[4][4];
#pragma unroll
        for (int n = 0; n < 4; ++n)
#pragma unroll
            for (int rg = 0; rg < 4; ++rg)
                bv[n][rg] = bias[co0 + wc * 64 + n * 16 + q * 4 + rg];
#pragma unroll
        for (int n = 0; n < 4; ++n) {
#pragma unroll
            for (int rg = 0; rg < 4; ++rg) {
                int co = co0 + wc * 64 + n * 16 + q * 4 + rg;
                float* orow = out + ((size_t)b * CC + co) * Lout;
                const float* rrow = resid + ((size_t)b * CC + co) * TTOT;
#pragma unroll
                for (int m = 0; m < 8; ++m) {
                    int t = t0 + wt * 128 + m * 16 + l15;
                    if (t < Lout)
                        orow[t] = acc[m][n][rg] + bv[n][rg] + rrow[t];
                }
            }
        }
    }
}

// ---------------------------------------------------------------------------
extern "C" void kernel_launch(void* const* d_in, const int* in_sizes, int n_in,
                              void* d_out, int out_size, void* d_ws, size_t ws_size,
                              hipStream_t stream)
{
    const float* x       = (const float*)d_in[0];
    const float* up_w1   = (const float*)d_in[1];
    const float* down_w1 = (const float*)d_in[2];
    const float* alpha1  = (const float*)d_in[3];
    const float* beta1   = (const float*)d_in[4];
    const float* up_w2   = (const float*)d_in[5];
    const float* down_w2 = (const float*)d_in[6];
    const float* alpha2  = (const float*)d_in[7];
    const float* beta2   = (const float*)d_in[8];
    const float* c1_w    = (const float*)d_in[9];
    const float* c1_b    = (const float*)d_in[10];
    const float* c2_w    = (const float*)d_in[11];
    const float* c2_b    = (const float*)d_in[12];
    float* out = (float*)d_out;

    u16* wr1 = (u16*)d_ws;                        // 786432 elems
    u16* wr2 = wr1 + 786432;
    u16* xTa = wr2 + 786432;                      // storage base (R=0), batch 0
    u16* xTb = xTa + (size_t)BB * BST;

    // weight transforms (tiny)
    wprep_kernel<<<1024, 256, 0, stream>>>(c1_w, wr1);
    wprep_kernel<<<1024, 256, 0, stream>>>(c2_w, wr2);
    // guard zeroing
    zguard_kernel<<<dim3(32, 8), 256, 0, stream>>>(xTa, LEN1);
    zguard_kernel<<<dim3(32, 8), 256, 0, stream>>>(xTb, LEN1);

    // act1: x (c-major f32, Lin=8192) -> xTa (chunk-row bf16, Lout=8190)
    actS_kernel<false><<<dim3(64, 16, 8), 256, 0, stream>>>(
        (const void*)x, xTa, up_w1, down_w1, alpha1, beta1, TTOT);
    // conv1: xTa -> xTb (chunk-row bf16), Lout=8190
    convg_kernel<0><<<dim3(32, 2, 8), 512, 0, stream>>>(
        xTa, wr1, c1_b, xTb, nullptr, nullptr, LEN1);
    // re-zero xTa guards for length LEN2 (act2 output reuses xTa)
    zguard_kernel<<<dim3(32, 8), 256, 0, stream>>>(xTa, LEN2);
    // act2: xTb (chunk-row bf16, Lin=8190) -> xTa (chunk-row bf16, Lout=8188)
    actS_kernel<true><<<dim3(64, 16, 8), 256, 0, stream>>>(
        (const void*)xTb, xTa, up_w2, down_w2, alpha2, beta2, LEN1);
    // conv2 + bias + residual: xTa -> out (c-major f32, Lout=8188)
    convg_kernel<1><<<dim3(32, 2, 8), 512, 0, stream>>>(
        xTa, wr2, c2_b, nullptr, out, x, LEN2);
}

// Round 5
// 614.590 us; speedup vs baseline: 1.0692x; 1.0692x over previous
//
#include <hip/hip_runtime.h>
#include <math.h>

#define CC 512
#define BB 8
#define TTOT 8192
#define LEN1 (TTOT - 2)   // 8190
#define LEN2 (TTOT - 4)   // 8188
#define GPRE 8
#define GPOST 24
#define PITCH (GPRE + TTOT + GPOST)   // 8224 storage rows
#define CHST (PITCH * 32)             // u16 per (batch,chunk) plane
#define BST (PITCH * 512)             // u16 per batch (16 chunks)

typedef unsigned short u16;
typedef __bf16 v8bf __attribute__((ext_vector_type(8)));
typedef float v4f __attribute__((ext_vector_type(4)));

__device__ __forceinline__ u16 f2b(float f) {
    unsigned u = __float_as_uint(f);
    unsigned r = (u + 0x7FFFu + ((u >> 16) & 1u)) >> 16;
    return (u16)r;
}
__device__ __forceinline__ float b2f(u16 h) {
    return __uint_as_float(((unsigned)h) << 16);
}
__device__ __forceinline__ void ldsdma16(const void* g, void* l) {
    __builtin_amdgcn_global_load_lds(
        (const __attribute__((address_space(1))) unsigned int*)g,
        (__attribute__((address_space(3))) unsigned int*)l, 16, 0, 0);
}

// ---------------------------------------------------------------------------
// X layout (xTa/xTb): [b][ci>>5][R][32ci] with R = GPRE + t (storage row).
// Within a row's 64B, granule g=(ci>>3)&3 is stored at slot s = g ^ ((R>>1)&3)
// (bank-conflict-free ds_read_b128 in convg; involution, read uses same XOR).
// W layout (wr): [ci>>5][k][co][32ci], slot s = g ^ ((co>>1)&3).
// ---------------------------------------------------------------------------

// Weight prep: w[co][ci][3] f32 -> chunked/swizzled bf16
__global__ __launch_bounds__(256) void wprep_kernel(const float* __restrict__ w,
                                                    u16* __restrict__ wr)
{
    int idx = blockIdx.x * 256 + threadIdx.x;     // co*512 + ci
    int co = idx >> 9, ci = idx & 511;
    const float* s = w + (size_t)idx * 3;
    int g = (ci >> 3) & 3;
    int slot = ((g ^ ((co >> 1) & 3)) << 3) | (ci & 7);
    size_t base = (size_t)(ci >> 5) * 3 * 16384 + (size_t)co * 32 + slot;
#pragma unroll
    for (int k = 0; k < 3; ++k)
        wr[base + (size_t)k * 16384] = f2b(s[k]);
}

// Zero guard rows R in [0,GPRE) and [GPRE+Lstart, GPRE+Lstart+GPOST), all chunks.
__global__ __launch_bounds__(256) void zguard_kernel(u16* x0, int Lstart)
{
    int r = blockIdx.x;            // 0..31
    int b = blockIdx.y;
    int R = (r < GPRE) ? r : (GPRE + Lstart + (r - GPRE));
    unsigned* p = (unsigned*)(x0 + (size_t)b * BST);
    int chunk = threadIdx.x >> 4, off = threadIdx.x & 15;
    p[(size_t)chunk * (CHST / 2) + (size_t)R * 16 + off] = 0u;
}

// ---------------------------------------------------------------------------
// Fused activation1d: coalesced LDS staging + register-ring streaming compute.
// (unchanged from round 3 — harness-verified)
// ---------------------------------------------------------------------------
template<bool TMAJ>
__global__ __launch_bounds__(256) void actS_kernel(
    const void* __restrict__ xin_v,
    u16* __restrict__ yout,          // storage base (R=0) of batch 0
    const float* __restrict__ up_w,  // [2C][6]
    const float* __restrict__ down_w,// [C][12]
    const float* __restrict__ alpha,
    const float* __restrict__ beta,
    int Lin)
{
    const int Lout = Lin - 2;
    const int smax = 2 * Lin - 4;
    const int tid  = threadIdx.x;
    const int cs   = tid & 31;           // channel within chunk
    const int tseg = tid >> 5;           // 0..7, 16 outputs each
    const int chunk = blockIdx.y;
    const int b     = blockIdx.z;
    const int T0    = blockIdx.x * 128;
    const int Tt    = T0 + tseg * 16;
    const int cg    = chunk * 32 + cs;

    __shared__ float xs[32 * 141];       // [c][i], 139 used per row

    // ---- stage x window g in [T0-4, T0+135) ----
    if (!TMAJ) {
        const float* xcb = (const float*)xin_v + ((size_t)b * CC + chunk * 32) * (size_t)Lin;
        int lane = tid & 63, w = tid >> 6;
#pragma unroll
        for (int rr = 0; rr < 8; ++rr) {
            int c = w * 8 + rr;
            const float* xr = xcb + (size_t)c * Lin;
            for (int i = lane; i < 139; i += 64) {
                int g = T0 - 4 + i;
                xs[c * 141 + i] = (g >= 0 && g < Lin) ? xr[g] : 0.0f;
            }
        }
    } else {
        const u16* xb = (const u16*)xin_v + (size_t)b * BST + (size_t)chunk * CHST;
        int pr = tid & 15, rq = tid >> 4;
#pragma unroll
        for (int r0 = 0; r0 < 139; r0 += 16) {
            int row = r0 + rq;
            if (row < 139) {
                int R = GPRE + T0 - 4 + row;   // guards cover both ends
                unsigned u = *((const unsigned*)(xb + (size_t)R * 32) + pr);
                int p2 = pr * 2;
                int c = (((p2 >> 3) ^ ((R >> 1) & 3)) << 3) | (p2 & 7);  // de-swizzle
                xs[c * 141 + row]       = b2f((u16)(u & 0xFFFFu));
                xs[(c + 1) * 141 + row] = b2f((u16)(u >> 16));
            }
        }
    }
    __syncthreads();

    // ---- per-thread register-ring compute ----
    const float a     = expf(alpha[cg]);
    const float inv2b = 1.0f / (2.0f * expf(beta[cg]) + 1e-9f);
    float uwa[6], uwb[6], dw[12];
#pragma unroll
    for (int k = 0; k < 6; ++k) {
        uwa[k] = up_w[(2 * cg) * 6 + k];
        uwb[k] = up_w[(2 * cg + 1) * 6 + k];
    }
#pragma unroll
    for (int j = 0; j < 12; ++j) dw[j] = down_w[cg * 12 + j];

    const float* xrow = xs + cs * 141 + tseg * 16;   // xrow[j] = x[Tt-4+j]

    float xw[12], sr[12];

    auto sval = [&](int idx) -> float {              // idx compile-time after unroll
        int s  = 2 * Tt - 5 + idx;
        int xo = (idx + 1) >> 1;
        float u = 0.0f;
#pragma unroll
        for (int k = 0; k < 6; ++k) {
            float wk = (idx & 1) ? uwa[k] : uwb[k];
            u = fmaf(xw[(xo + k) % 12], wk, u);
        }
        float v = fmaf(1.0f - __cosf(2.0f * a * u), inv2b, u);
        return (s >= 0 && s < smax) ? v : 0.0f;
    };

    // prologue: xw holds x[Tt-4 .. Tt+6]
#pragma unroll
    for (int j = 0; j < 11; ++j) xw[j] = xrow[j];
    xw[11] = 0.0f;
#pragma unroll
    for (int idx = 0; idx < 10; ++idx) sr[idx] = sval(idx);

    u16* yb = yout + (size_t)b * BST + (size_t)chunk * CHST;

#pragma unroll
    for (int i = 0; i < 16; ++i) {
        xw[(11 + i) % 12] = xrow[11 + i];            // x[Tt+7+i]
        sr[(10 + 2 * i) % 12] = sval(10 + 2 * i);
        sr[(11 + 2 * i) % 12] = sval(11 + 2 * i);
        float y = 0.0f;
#pragma unroll
        for (int j = 0; j < 12; ++j)
            y = fmaf(sr[(2 * i + j) % 12], dw[j], y);
        int t = Tt + i;
        if (t < Lout) {
            int R = GPRE + t;
            int slot = (((cs >> 3) ^ ((R >> 1) & 3)) << 3) | (cs & 7);
            yb[(size_t)R * 32 + slot] = f2b(y);
        }
    }
}

// ---------------------------------------------------------------------------
// k=3 pad=1 conv as bf16 MFMA GEMM over chunk-row input — m97 configuration.
// Tile 128 t x 128 co, 4 waves of 64x64, BK=32 ci, single-buffer 2-barrier loop.
// acc[4][4] = 64 AGPRs -> ~148 total regs -> 3 waves/SIMD -> 3 blocks/CU
// (implicit cross-block overlap hides staging; m114/m97).
// ---------------------------------------------------------------------------
template<int ORIENT>
__global__ __launch_bounds__(256, 3) void convg_kernel(
    const u16* __restrict__ xt,     // storage base (R=0) of batch 0
    const u16* __restrict__ wr,     // [16][3][512][32] swizzled bf16
    const float* __restrict__ bias, // [512]
    u16* __restrict__ yt,           // ORIENT 0 output (storage base)
    float* __restrict__ out,        // ORIENT 1 output (B,C,Lout)
    const float* __restrict__ resid,// ORIENT 1 residual (B,C,TTOT)
    int Lout)
{
    const int tid  = threadIdx.x;
    const int lane = tid & 63, wid = tid >> 6;
    const int wt = wid & 1, wc = wid >> 1;
    const int l15 = lane & 15, q = lane >> 4;
    const int t0  = blockIdx.x * 128;
    const int co0 = blockIdx.y * 128;
    const int b   = blockIdx.z;

    __shared__ __align__(16) u16 xsm[136 * 32];      // [row][32ci], 8.7 KB
    __shared__ __align__(16) u16 wsm[3 * 128 * 32];  // [k][co_l][32ci], 24.6 KB

    const u16* xb = xt + (size_t)b * BST;
    const int R0 = GPRE + t0 - 1;   // storage row of LDS row 0 (>= 7)

    v4f acc[4][4];
#pragma unroll
    for (int m = 0; m < 4; ++m)
#pragma unroll
        for (int n = 0; n < 4; ++n)
#pragma unroll
            for (int r = 0; r < 4; ++r) acc[m][n][r] = 0.0f;

    for (int cig = 0; cig < 16; ++cig) {
        const u16* xsl = xb + (size_t)cig * CHST + (size_t)R0 * 32;
        const u16* wsl = wr + (size_t)cig * 49152 + (size_t)co0 * 32;

        // ---- stage X: 136 rows x 64B contiguous; 544 granules, 9 wave-ops ----
#pragma unroll
        for (int j = 0; j < 3; ++j) {
            int ii = wid + 4 * j;
            if (ii < 9) {
                int task = ii * 64 + lane;
                if (task < 544)
                    ldsdma16(xsl + (size_t)task * 8, xsm + (size_t)ii * 512);
            }
        }
        // ---- stage W: 3 slabs of 128co x 64B contiguous; 1536 granules, 24 ops ----
#pragma unroll
        for (int j = 0; j < 6; ++j) {
            int ii = wid + 4 * j;    // <= 23; k = ii>>3 uniform per op
            ldsdma16(wsl + (size_t)(ii * 64 + lane) * 8 + (size_t)(ii >> 3) * 12288,
                     wsm + (size_t)ii * 512);
        }
        __syncthreads();

#pragma unroll
        for (int k = 0; k < 3; ++k) {
            v8bf wf[4];
#pragma unroll
            for (int n = 0; n < 4; ++n) {
                int co_l = wc * 64 + n * 16 + l15;
                wf[n] = *(const v8bf*)(wsm + ((k * 128 + co_l) << 5)
                                           + ((q ^ ((co_l >> 1) & 3)) << 3));
            }
#pragma unroll
            for (int m = 0; m < 4; ++m) {
                int r = wt * 64 + m * 16 + l15 + k;      // storage row R0+r
                v8bf xf = *(const v8bf*)(xsm + (r << 5)
                                             + ((q ^ (((r + 7) >> 1) & 3)) << 3));
#pragma unroll
                for (int n = 0; n < 4; ++n) {
                    if (ORIENT == 0)
                        acc[m][n] = __builtin_amdgcn_mfma_f32_16x16x32_bf16(
                            xf, wf[n], acc[m][n], 0, 0, 0);
                    else
                        acc[m][n] = __builtin_amdgcn_mfma_f32_16x16x32_bf16(
                            wf[n], xf, acc[m][n], 0, 0, 0);
                }
            }
        }
        __syncthreads();
    }

    if (ORIENT == 0) {
        // D[m=t][n=co]: col(lane&15)=co, row(q*4+reg)=t-local; write chunk-row bf16
        float bv[4];
#pragma unroll
        for (int n = 0; n < 4; ++n) bv[n] = bias[co0 + wc * 64 + n * 16 + l15];
        u16* yb = yt + (size_t)b * BST;
        int cb = (co0 + wc * 64) >> 5;    // chunk base
#pragma unroll
        for (int m = 0; m < 4; ++m) {
            int tb = t0 + wt * 64 + m * 16;
#pragma unroll
            for (int rg = 0; rg < 4; ++rg) {
                int t = tb + q * 4 + rg;
                if (t < Lout) {
                    int R = GPRE + t;
                    int f = (R >> 1) & 3;
#pragma unroll
                    for (int n = 0; n < 4; ++n) {
                        int cl = ((n & 1) << 4) | l15;
                        int slot = (((cl >> 3) ^ f) << 3) | (cl & 7);
                        yb[(size_t)(cb + (n >> 1)) * CHST + (size_t)R * 32 + slot]
                            = f2b(acc[m][n][rg] + bv[n]);
                    }
                }
            }
        }
    } else {
        // D[m=co][n=t]: col(lane&15)=t-local, row(q*4+reg)=co-local
        float bv[4][4];
#pragma unroll
        for (int n = 0; n < 4; ++n)
#pragma unroll
            for (int rg = 0; rg < 4; ++rg)
                bv[n][rg] = bias[co0 + wc * 64 + n * 16 + q * 4 + rg];
#pragma unroll
        for (int n = 0; n < 4; ++n) {
#pragma unroll
            for (int rg = 0; rg < 4; ++rg) {
                int co = co0 + wc * 64 + n * 16 + q * 4 + rg;
                float* orow = out + ((size_t)b * CC + co) * Lout;
                const float* rrow = resid + ((size_t)b * CC + co) * TTOT;
#pragma unroll
                for (int m = 0; m < 4; ++m) {
                    int t = t0 + wt * 64 + m * 16 + l15;
                    if (t < Lout)
                        orow[t] = acc[m][n][rg] + bv[n][rg] + rrow[t];
                }
            }
        }
    }
}

// ---------------------------------------------------------------------------
extern "C" void kernel_launch(void* const* d_in, const int* in_sizes, int n_in,
                              void* d_out, int out_size, void* d_ws, size_t ws_size,
                              hipStream_t stream)
{
    const float* x       = (const float*)d_in[0];
    const float* up_w1   = (const float*)d_in[1];
    const float* down_w1 = (const float*)d_in[2];
    const float* alpha1  = (const float*)d_in[3];
    const float* beta1   = (const float*)d_in[4];
    const float* up_w2   = (const float*)d_in[5];
    const float* down_w2 = (const float*)d_in[6];
    const float* alpha2  = (const float*)d_in[7];
    const float* beta2   = (const float*)d_in[8];
    const float* c1_w    = (const float*)d_in[9];
    const float* c1_b    = (const float*)d_in[10];
    const float* c2_w    = (const float*)d_in[11];
    const float* c2_b    = (const float*)d_in[12];
    float* out = (float*)d_out;

    u16* wr1 = (u16*)d_ws;                        // 786432 elems
    u16* wr2 = wr1 + 786432;
    u16* xTa = wr2 + 786432;                      // storage base (R=0), batch 0
    u16* xTb = xTa + (size_t)BB * BST;

    // weight transforms (tiny)
    wprep_kernel<<<1024, 256, 0, stream>>>(c1_w, wr1);
    wprep_kernel<<<1024, 256, 0, stream>>>(c2_w, wr2);
    // guard zeroing
    zguard_kernel<<<dim3(32, 8), 256, 0, stream>>>(xTa, LEN1);
    zguard_kernel<<<dim3(32, 8), 256, 0, stream>>>(xTb, LEN1);

    // act1: x (c-major f32, Lin=8192) -> xTa (chunk-row bf16, Lout=8190)
    actS_kernel<false><<<dim3(64, 16, 8), 256, 0, stream>>>(
        (const void*)x, xTa, up_w1, down_w1, alpha1, beta1, TTOT);
    // conv1: xTa -> xTb (chunk-row bf16), Lout=8190
    convg_kernel<0><<<dim3(64, 4, 8), 256, 0, stream>>>(
        xTa, wr1, c1_b, xTb, nullptr, nullptr, LEN1);
    // re-zero xTa guards for length LEN2 (act2 output reuses xTa)
    zguard_kernel<<<dim3(32, 8), 256, 0, stream>>>(xTa, LEN2);
    // act2: xTb (chunk-row bf16, Lin=8190) -> xTa (chunk-row bf16, Lout=8188)
    actS_kernel<true><<<dim3(64, 16, 8), 256, 0, stream>>>(
        (const void*)xTb, xTa, up_w2, down_w2, alpha2, beta2, LEN1);
    // conv2 + bias + residual: xTa -> out (c-major f32, Lout=8188)
    convg_kernel<1><<<dim3(64, 4, 8), 256, 0, stream>>>(
        xTa, wr2, c2_b, nullptr, out, x, LEN2);
}